// Round 11
// baseline (955.046 us; speedup 1.0000x reference)
//
#include <hip/hip_runtime.h>
#include <hip/hip_bf16.h>

#define NN 50000
#define NE 800000
#define NET (NE + NN)
#define SCAN_NB ((NN + 255) / 256)   // 196

static inline int imin(int a, int b) { return a < b ? a : b; }

typedef _Float16 half8 __attribute__((ext_vector_type(8)));
typedef _Float16 half2v __attribute__((ext_vector_type(2)));
typedef float f32x4 __attribute__((ext_vector_type(4)));

// ---------------- CSR build (graph constant across layers) ----------------
__global__ void k_count(const int* __restrict__ edst, int* __restrict__ counts) {
    int e = blockIdx.x * blockDim.x + threadIdx.x;
    if (e >= NET) return;
    int d = (e < NE) ? edst[e] : (e - NE);   // self loops appended
    atomicAdd(&counts[d], 1);
}

__global__ __launch_bounds__(256) void k_scan1(const int* __restrict__ counts,
                                               int* __restrict__ part) {
    __shared__ int s[256];
    int t = threadIdx.x, i = blockIdx.x * 256 + t;
    s[t] = (i < NN) ? counts[i] : 0;
    __syncthreads();
    for (int off = 128; off > 0; off >>= 1) {
        if (t < off) s[t] += s[t + off];
        __syncthreads();
    }
    if (t == 0) part[blockIdx.x] = s[0];
}

__global__ __launch_bounds__(256) void k_scan2(int* __restrict__ part, int* __restrict__ offs) {
    __shared__ int s[256];
    int t = threadIdx.x;
    int v = (t < SCAN_NB) ? part[t] : 0;
    s[t] = v;
    __syncthreads();
    for (int off = 1; off < 256; off <<= 1) {
        int a = (t >= off) ? s[t - off] : 0;
        __syncthreads();
        s[t] += a;
        __syncthreads();
    }
    if (t < SCAN_NB) part[t] = s[t] - v;     // exclusive block offsets
    if (t == 255) offs[NN] = s[255];         // total (= NET)
}

__global__ __launch_bounds__(256) void k_scan3(const int* __restrict__ counts,
                                               const int* __restrict__ part,
                                               int* __restrict__ offs, int* __restrict__ cursor) {
    __shared__ int s[256];
    int t = threadIdx.x, i = blockIdx.x * 256 + t;
    int v = (i < NN) ? counts[i] : 0;
    s[t] = v;
    __syncthreads();
    for (int off = 1; off < 256; off <<= 1) {
        int a = (t >= off) ? s[t - off] : 0;
        __syncthreads();
        s[t] += a;
        __syncthreads();
    }
    if (i < NN) {
        int e = part[blockIdx.x] + s[t] - v;
        offs[i] = e;
        cursor[i] = e;
    }
}

__global__ void k_scatter(const int* __restrict__ esrc, const int* __restrict__ edst,
                          int* __restrict__ cursor, int* __restrict__ csr_src) {
    int e = blockIdx.x * blockDim.x + threadIdx.x;
    if (e >= NET) return;
    int s, d;
    if (e < NE) { s = esrc[e]; d = edst[e]; } else { s = e - NE; d = s; }
    int pos = atomicAdd(&cursor[d], 1);
    csr_src[pos] = s;
}

// ---------------- split fp32 -> f16 hi/lo pair ----------------
__global__ void k_split(const float* __restrict__ in, _Float16* __restrict__ hi,
                        _Float16* __restrict__ lo, int n) {
    int i = blockIdx.x * blockDim.x + threadIdx.x;
    int st = gridDim.x * blockDim.x;
    for (; i < n; i += st) {
        float v = in[i];
        _Float16 h = (_Float16)v;
        hi[i] = h;
        lo[i] = (_Float16)(v - (float)h);
    }
}

// ---------------- transpose + split weights: W[K][N] -> T[N][K] hi/lo (LDS-tiled) ----
__global__ __launch_bounds__(256) void k_prepw(const float* __restrict__ W,
                                               _Float16* __restrict__ Th,
                                               _Float16* __restrict__ Tl, int K, int N) {
    __shared__ float tile[32][33];
    int tx = threadIdx.x & 31, ty = threadIdx.x >> 5;
    int n0 = blockIdx.x * 32, k0 = blockIdx.y * 32;
    #pragma unroll
    for (int r = ty; r < 32; r += 8)
        tile[r][tx] = W[(size_t)(k0 + r) * N + n0 + tx];   // coalesced read
    __syncthreads();
    #pragma unroll
    for (int r = ty; r < 32; r += 8) {
        int n = n0 + r, k = k0 + tx;
        float v = tile[tx][r];
        _Float16 h = (_Float16)v;
        Th[(size_t)n * K + k] = h;                          // coalesced 64B segments
        Tl[(size_t)n * K + k] = (_Float16)(v - (float)h);
    }
}

// ---------------- per-node attention scalars: s = h . a ----------------
__global__ void k_scalars(const float* __restrict__ h, const float* __restrict__ a_src,
                          const float* __restrict__ a_dst, float* __restrict__ s_src,
                          float* __restrict__ s_dst) {
    int node = blockIdx.x * 4 + (threadIdx.x >> 6);
    int lane = threadIdx.x & 63;
    if (node >= NN) return;
    const float2* hr = (const float2*)(h + (size_t)node * 128) + lane;
    float2 hv = *hr;
    float2 as = *((const float2*)a_src + lane);
    float2 ad = *((const float2*)a_dst + lane);
    float ps = hv.x * as.x + hv.y * as.y;
    float pd = hv.x * ad.x + hv.y * ad.y;
    #pragma unroll
    for (int off = 32; off > 0; off >>= 1) {
        ps += __shfl_down(ps, off);
        pd += __shfl_down(pd, off);
    }
    if (lane == 0) { s_src[node] = ps; s_dst[node] = pd; }
}

// ---------------- fused segment-softmax + aggregate + bias + leaky ----------------
// 4-edge unroll (latency-bound gather); float2 per-lane row gather (1 load not 2).
__global__ void k_aggregate(const float* __restrict__ h, const float* __restrict__ s_src,
                            const float* __restrict__ s_dst, const int* __restrict__ offs,
                            const int* __restrict__ csr_src, const float* __restrict__ bias,
                            _Float16* __restrict__ xh, _Float16* __restrict__ xl) {
    int node = blockIdx.x * 4 + (threadIdx.x >> 6);
    int lane = threadIdx.x & 63;
    if (node >= NN) return;
    int p = offs[node], pe = offs[node + 1];
    float sd = s_dst[node];
    float den = 0.f, acc0 = 0.f, acc1 = 0.f;
    for (; p + 4 <= pe; p += 4) {
        int s0 = csr_src[p + 0], s1 = csr_src[p + 1];
        int s2 = csr_src[p + 2], s3 = csr_src[p + 3];
        float e0 = s_src[s0] + sd, e1 = s_src[s1] + sd;
        float e2 = s_src[s2] + sd, e3 = s_src[s3] + sd;
        float2 a0 = *((const float2*)(h + (size_t)s0 * 128) + lane);
        float2 a1 = *((const float2*)(h + (size_t)s1 * 128) + lane);
        float2 a2 = *((const float2*)(h + (size_t)s2 * 128) + lane);
        float2 a3 = *((const float2*)(h + (size_t)s3 * 128) + lane);
        e0 = (e0 > 0.f) ? e0 : 0.2f * e0;  float w0 = __expf(e0);
        e1 = (e1 > 0.f) ? e1 : 0.2f * e1;  float w1 = __expf(e1);
        e2 = (e2 > 0.f) ? e2 : 0.2f * e2;  float w2 = __expf(e2);
        e3 = (e3 > 0.f) ? e3 : 0.2f * e3;  float w3 = __expf(e3);
        den += (w0 + w1) + (w2 + w3);
        acc0 += w0 * a0.x + w1 * a1.x + w2 * a2.x + w3 * a3.x;
        acc1 += w0 * a0.y + w1 * a1.y + w2 * a2.y + w3 * a3.y;
    }
    for (; p < pe; ++p) {
        int src = csr_src[p];
        float e = s_src[src] + sd;
        e = (e > 0.f) ? e : 0.2f * e;
        float wgt = __expf(e);
        den += wgt;
        float2 av = *((const float2*)(h + (size_t)src * 128) + lane);
        acc0 += wgt * av.x;
        acc1 += wgt * av.y;
    }
    float inv = 1.f / den;                    // self-loop guarantees den > 0
    float2 bv = *((const float2*)bias + lane);
    float v0 = acc0 * inv + bv.x;
    float v1 = acc1 * inv + bv.y;
    v0 = (v0 > 0.f) ? v0 : 0.2f * v0;
    v1 = (v1 > 0.f) ? v1 : 0.2f * v1;
    _Float16 h0 = (_Float16)v0, h1 = (_Float16)v1;
    size_t base = (size_t)node * 128 + 2 * lane;
    *(half2v*)(xh + base) = (half2v){h0, h1};
    *(half2v*)(xl + base) = (half2v){(_Float16)(v0 - (float)h0), (_Float16)(v1 - (float)h1)};
}

// ---------------- split-f16 MFMA GEMM: reg-dbuf + fragment-major LDS ----------------
// C[M][N] = act(A[M][K] @ B^T[N][K] + bias), A,B as f16 hi/lo pairs,
// A·B ≈ Ahi·Bhi + Ahi·Blo + Alo·Bhi (fp32 MFMA accumulate).
// 128x128 tile, 4 waves (2x2), each wave 64x64 = 4x4 of 16x16x32 MFMA. BK=32.
// LDS is FRAGMENT-MAJOR [frag(8)][lane(64)*16B]. STAGING USES THE SAME
// LANE-CONTIGUOUS MAPPING AS THE READS (R8: measured 0 conflicts):
// wave w stages frags {2w,2w+1} of each panel; lane l fetches global
// row = frag*16 + (l&15), k-chunk (l>>4)*8 and stores at frag*1024 + l*16.
// (R10's permuted store slot=(t>>2)+16*(t&3) put 4 consecutive lanes on one
// bank quad -> 1.73e7 conflict cycles. This mapping fixes that; global
// footprint per wave identical, VMEM coalescing is order-insensitive.)
// K-loop is reg-double-buffered: store staged regs -> sync -> issue NEXT
// K-step's loads -> compute (loads overlap MFMA).
// XCD-aware 1D tile order (R7): contiguous tile runs per XCD L2.
__global__ __launch_bounds__(256) void k_mgemm(
    const _Float16* __restrict__ Ahi, const _Float16* __restrict__ Alo,
    const _Float16* __restrict__ Bhi, const _Float16* __restrict__ Blo,
    const float* __restrict__ bias, float* __restrict__ Cf,
    _Float16* __restrict__ Chi, _Float16* __restrict__ Clo,
    int M, int N, int K, int relu, int split, int nx, int ntiles)
{
    __shared__ _Float16 sAh[8 * 512];   // 8 frags x 1KB = 8KB each, 32KB total
    __shared__ _Float16 sAl[8 * 512];
    __shared__ _Float16 sBh[8 * 512];
    __shared__ _Float16 sBl[8 * 512];

    int bid = blockIdx.x;
    int per = (ntiles + 7) >> 3;
    int g = (bid & 7) * per + (bid >> 3);
    if (g >= ntiles) return;
    int col0 = (g % nx) * 128;
    int row0 = (g / nx) * 128;

    int t = threadIdx.x;
    int w = t >> 6, lane = t & 63;
    int fr = lane & 15;
    int fq = lane >> 4;

    // staging: wave w owns frags {2w, 2w+1}; lane-contiguous LDS addressing
    int f0 = 2 * w, f1 = 2 * w + 1;
    int rA0 = row0 + f0 * 16 + fr; if (rA0 > M - 1) rA0 = M - 1;   // clamp OOB rows
    int rA1 = row0 + f1 * 16 + fr; if (rA1 > M - 1) rA1 = M - 1;
    int rB0 = col0 + f0 * 16 + fr;
    int rB1 = col0 + f1 * 16 + fr;
    const _Float16* pAh0 = Ahi + (size_t)rA0 * K + fq * 8;
    const _Float16* pAh1 = Ahi + (size_t)rA1 * K + fq * 8;
    const _Float16* pAl0 = Alo + (size_t)rA0 * K + fq * 8;
    const _Float16* pAl1 = Alo + (size_t)rA1 * K + fq * 8;
    const _Float16* pBh0 = Bhi + (size_t)rB0 * K + fq * 8;
    const _Float16* pBh1 = Bhi + (size_t)rB1 * K + fq * 8;
    const _Float16* pBl0 = Blo + (size_t)rB0 * K + fq * 8;
    const _Float16* pBl1 = Blo + (size_t)rB1 * K + fq * 8;
    _Float16* dAh0 = sAh + f0 * 512 + lane * 8;
    _Float16* dAh1 = sAh + f1 * 512 + lane * 8;
    _Float16* dAl0 = sAl + f0 * 512 + lane * 8;
    _Float16* dAl1 = sAl + f1 * 512 + lane * 8;
    _Float16* dBh0 = sBh + f0 * 512 + lane * 8;
    _Float16* dBh1 = sBh + f1 * 512 + lane * 8;
    _Float16* dBl0 = sBl + f0 * 512 + lane * 8;
    _Float16* dBl1 = sBl + f1 * 512 + lane * 8;

    // compute-side frag groups
    int faw = (w & 1) * 4;
    int fbw = (w >> 1) * 4;

    f32x4 acc[4][4];
    #pragma unroll
    for (int i = 0; i < 4; i++)
        #pragma unroll
        for (int j = 0; j < 4; j++) acc[i][j] = (f32x4){0.f, 0.f, 0.f, 0.f};

    // prefetch K-step 0 into registers
    half8 vAh0 = *(const half8*)pAh0, vAh1 = *(const half8*)pAh1;
    half8 vAl0 = *(const half8*)pAl0, vAl1 = *(const half8*)pAl1;
    half8 vBh0 = *(const half8*)pBh0, vBh1 = *(const half8*)pBh1;
    half8 vBl0 = *(const half8*)pBl0, vBl1 = *(const half8*)pBl1;

    for (int k0 = 0; k0 < K; k0 += 32) {
        if (k0) __syncthreads();             // previous compute done reading LDS
        *(half8*)dAh0 = vAh0; *(half8*)dAh1 = vAh1;
        *(half8*)dAl0 = vAl0; *(half8*)dAl1 = vAl1;
        *(half8*)dBh0 = vBh0; *(half8*)dBh1 = vBh1;
        *(half8*)dBl0 = vBl0; *(half8*)dBl1 = vBl1;
        __syncthreads();
        if (k0 + 32 < K) {                   // issue next loads; overlap with MFMA below
            int kn = k0 + 32;
            vAh0 = *(const half8*)(pAh0 + kn); vAh1 = *(const half8*)(pAh1 + kn);
            vAl0 = *(const half8*)(pAl0 + kn); vAl1 = *(const half8*)(pAl1 + kn);
            vBh0 = *(const half8*)(pBh0 + kn); vBh1 = *(const half8*)(pBh1 + kn);
            vBl0 = *(const half8*)(pBl0 + kn); vBl1 = *(const half8*)(pBl1 + kn);
        }

        half8 bh[4], bl[4];
        #pragma unroll
        for (int ni = 0; ni < 4; ++ni) {
            bh[ni] = *(const half8*)(sBh + (fbw + ni) * 512 + lane * 8);
            bl[ni] = *(const half8*)(sBl + (fbw + ni) * 512 + lane * 8);
        }
        #pragma unroll
        for (int mi = 0; mi < 4; ++mi) {
            half8 ah = *(const half8*)(sAh + (faw + mi) * 512 + lane * 8);
            half8 al = *(const half8*)(sAl + (faw + mi) * 512 + lane * 8);
            #pragma unroll
            for (int ni = 0; ni < 4; ++ni) {
                acc[mi][ni] = __builtin_amdgcn_mfma_f32_16x16x32_f16(ah, bh[ni], acc[mi][ni], 0, 0, 0);
                acc[mi][ni] = __builtin_amdgcn_mfma_f32_16x16x32_f16(ah, bl[ni], acc[mi][ni], 0, 0, 0);
                acc[mi][ni] = __builtin_amdgcn_mfma_f32_16x16x32_f16(al, bh[ni], acc[mi][ni], 0, 0, 0);
            }
        }
    }

    // epilogue: C/D layout col=lane&15, row=quad*4+reg
    int wm = (w & 1) * 64, wn = (w >> 1) * 64;
    #pragma unroll
    for (int ni = 0; ni < 4; ++ni) {
        int gc = col0 + wn + ni * 16 + fr;
        float bv = bias ? bias[gc] : 0.f;
        #pragma unroll
        for (int mi = 0; mi < 4; ++mi) {
            #pragma unroll
            for (int r = 0; r < 4; ++r) {
                int gr = row0 + wm + mi * 16 + fq * 4 + r;
                if (gr >= M) continue;
                float v = acc[mi][ni][r] + bv;
                if (relu) v = (v > 0.f) ? v : 0.f;
                size_t idx = (size_t)gr * N + gc;
                if (split) {
                    _Float16 hh = (_Float16)v;
                    Chi[idx] = hh;
                    Clo[idx] = (_Float16)(v - (float)hh);
                } else {
                    Cf[idx] = v;
                }
            }
        }
    }
}

// ---------------- head: out[M x 4] = (Yh+Yl)[M x 512] @ Wo[512 x 4] + bo ----------------
__global__ __launch_bounds__(256) void k_head(const _Float16* __restrict__ Yh,
                                              const _Float16* __restrict__ Yl,
                                              const float* __restrict__ Wo,
                                              const float* __restrict__ bo,
                                              float* __restrict__ out, int M) {
    int node = blockIdx.x * 4 + (threadIdx.x >> 6);
    int lane = threadIdx.x & 63;
    if (node >= M) return;
    size_t base = (size_t)node * 512 + lane * 8;
    half8 hv = *(const half8*)(Yh + base);
    half8 lv = *(const half8*)(Yl + base);
    float a0 = 0.f, a1 = 0.f, a2 = 0.f, a3 = 0.f;
    #pragma unroll
    for (int i = 0; i < 8; i++) {
        float y = (float)hv[i] + (float)lv[i];
        float4 wv = *(const float4*)(Wo + (size_t)(lane * 8 + i) * 4);
        a0 += y * wv.x; a1 += y * wv.y;
        a2 += y * wv.z; a3 += y * wv.w;
    }
    #pragma unroll
    for (int off = 32; off > 0; off >>= 1) {
        a0 += __shfl_down(a0, off);
        a1 += __shfl_down(a1, off);
        a2 += __shfl_down(a2, off);
        a3 += __shfl_down(a3, off);
    }
    if (lane == 0) {
        float4 o;
        o.x = a0 + bo[0]; o.y = a1 + bo[1]; o.z = a2 + bo[2]; o.w = a3 + bo[3];
        *(float4*)(out + (size_t)node * 4) = o;
    }
}

extern "C" void kernel_launch(void* const* d_in, const int* in_sizes, int n_in,
                              void* d_out, int out_size, void* d_ws, size_t ws_size,
                              hipStream_t stream) {
    const float* x    = (const float*)d_in[0];
    const int*   eidx = (const int*)d_in[1];
    const float* cW   = (const float*)d_in[2];
    const float* caS  = (const float*)d_in[3];
    const float* caD  = (const float*)d_in[4];
    const float* cB   = (const float*)d_in[5];
    const float* W0   = (const float*)d_in[6];
    const float* b0   = (const float*)d_in[7];
    const float* W1   = (const float*)d_in[8];
    const float* b1   = (const float*)d_in[9];
    const float* W2   = (const float*)d_in[10];
    const float* b2   = (const float*)d_in[11];
    const float* Wo   = (const float*)d_in[12];
    const float* bo   = (const float*)d_in[13];
    (void)in_sizes; (void)n_in; (void)out_size;

    const int* esrc = eidx;
    const int* edst = eidx + NE;
    float* out = (float*)d_out;

    // ---- workspace bump allocator (256B aligned) ----
    char* w = (char*)d_ws;
    auto alloc = [&](size_t bytes) -> char* {
        char* p = w;
        w += (bytes + 255) & ~(size_t)255;
        return p;
    };
    _Float16* x0h  = (_Float16*)alloc((size_t)NN * 128 * 2);
    _Float16* x0l  = (_Float16*)alloc((size_t)NN * 128 * 2);
    _Float16* xh   = (_Float16*)alloc((size_t)NN * 128 * 2);
    _Float16* xl   = (_Float16*)alloc((size_t)NN * 128 * 2);
    float* hbuf    = (float*)alloc((size_t)NN * 128 * 4);
    float* ssrc    = (float*)alloc((size_t)NN * 4);
    float* sdst    = (float*)alloc((size_t)NN * 4);
    int*   counts  = (int*)  alloc((size_t)NN * 4);
    int*   offs    = (int*)  alloc((size_t)(NN + 1) * 4);
    int*   cursor  = (int*)  alloc((size_t)NN * 4);
    int*   csr     = (int*)  alloc((size_t)NET * 4);
    int*   part    = (int*)  alloc((size_t)SCAN_NB * 4);
    _Float16* cwh  = (_Float16*)alloc(3 * 128 * 128 * 2);
    _Float16* cwl  = (_Float16*)alloc(3 * 128 * 128 * 2);
    _Float16* w0h  = (_Float16*)alloc(512 * 128 * 2);
    _Float16* w0l  = (_Float16*)alloc(512 * 128 * 2);
    _Float16* w1h  = (_Float16*)alloc(512 * 512 * 2);
    _Float16* w1l  = (_Float16*)alloc(512 * 512 * 2);
    _Float16* w2h  = (_Float16*)alloc(512 * 512 * 2);
    _Float16* w2l  = (_Float16*)alloc(512 * 512 * 2);

    size_t used = (size_t)(w - (char*)d_ws);
    size_t rem = (ws_size > used) ? (ws_size - used) : 0;
    int chunk = (int)(rem / (4 * 512 * sizeof(_Float16)));
    if (chunk > NN) chunk = NN;
    if (chunk > 128) chunk &= ~127;
    if (chunk < 1) chunk = 1;
    _Float16* Y0h = (_Float16*)alloc((size_t)chunk * 512 * 2);
    _Float16* Y0l = (_Float16*)alloc((size_t)chunk * 512 * 2);
    _Float16* Y1h = (_Float16*)alloc((size_t)chunk * 512 * 2);
    _Float16* Y1l = (_Float16*)alloc((size_t)chunk * 512 * 2);

    auto gemm = [&](const _Float16* Ah, const _Float16* Al,
                    const _Float16* Bh, const _Float16* Bl,
                    const float* bias, float* Cf, _Float16* Ch, _Float16* Cl,
                    int M, int N, int K, int relu, int split) {
        int nx = N / 128;
        int ntiles = nx * ((M + 127) / 128);
        int nb = ((ntiles + 7) / 8) * 8;
        k_mgemm<<<nb, 256, 0, stream>>>(Ah, Al, Bh, Bl, bias, Cf, Ch, Cl,
                                        M, N, K, relu, split, nx, ntiles);
    };

    // ---- prep: split x, transpose+split weights ----
    k_split<<<2048, 256, 0, stream>>>(x, x0h, x0l, NN * 128);
    for (int L = 0; L < 3; ++L)
        k_prepw<<<dim3(128 / 32, 128 / 32), 256, 0, stream>>>(
            cW + (size_t)L * 128 * 128, cwh + (size_t)L * 128 * 128, cwl + (size_t)L * 128 * 128, 128, 128);
    k_prepw<<<dim3(512 / 32, 128 / 32), 256, 0, stream>>>(W0, w0h, w0l, 128, 512);
    k_prepw<<<dim3(512 / 32, 512 / 32), 256, 0, stream>>>(W1, w1h, w1l, 512, 512);
    k_prepw<<<dim3(512 / 32, 512 / 32), 256, 0, stream>>>(W2, w2h, w2l, 512, 512);

    // ---- build CSR once ----
    hipMemsetAsync(counts, 0, (size_t)NN * 4, stream);
    int eblocks = (NET + 255) / 256;
    k_count <<<eblocks, 256, 0, stream>>>(edst, counts);
    k_scan1 <<<SCAN_NB, 256, 0, stream>>>(counts, part);
    k_scan2 <<<1, 256, 0, stream>>>(part, offs);
    k_scan3 <<<SCAN_NB, 256, 0, stream>>>(counts, part, offs, cursor);
    k_scatter<<<eblocks, 256, 0, stream>>>(esrc, edst, cursor, csr);

    // ---- 3 GAT layers ----
    for (int L = 0; L < 3; ++L) {
        const _Float16* Ah = (L == 0) ? x0h : xh;
        const _Float16* Al = (L == 0) ? x0l : xl;
        gemm(Ah, Al, cwh + (size_t)L * 128 * 128, cwl + (size_t)L * 128 * 128,
             nullptr, hbuf, nullptr, nullptr, NN, 128, 128, 0, 0);
        k_scalars  <<<NN / 4, 256, 0, stream>>>(hbuf, caS + L * 128, caD + L * 128, ssrc, sdst);
        k_aggregate<<<NN / 4, 256, 0, stream>>>(hbuf, ssrc, sdst, offs, csr, cB + L * 128, xh, xl);
    }

    // ---- MLP head (chunked over nodes) ----
    for (int m0 = 0; m0 < NN; m0 += chunk) {
        int cm = imin(chunk, NN - m0);
        gemm(xh + (size_t)m0 * 128, xl + (size_t)m0 * 128, w0h, w0l, b0,
             nullptr, Y0h, Y0l, cm, 512, 128, 1, 1);
        gemm(Y0h, Y0l, w1h, w1l, b1, nullptr, Y1h, Y1l, cm, 512, 512, 1, 1);
        gemm(Y1h, Y1l, w2h, w2l, b2, nullptr, Y0h, Y0l, cm, 512, 512, 1, 1);
        k_head<<<(cm + 3) / 4, 256, 0, stream>>>(Y0h, Y0l, Wo, bo, out + (size_t)m0 * 4, cm);
    }
}

// Round 12
// 883.239 us; speedup vs baseline: 1.0813x; 1.0813x over previous
//
#include <hip/hip_runtime.h>
#include <hip/hip_bf16.h>

#define NN 50000
#define NE 800000
#define NET (NE + NN)
#define SCAN_NB ((NN + 255) / 256)   // 196

static inline int imin(int a, int b) { return a < b ? a : b; }

typedef _Float16 half8 __attribute__((ext_vector_type(8)));
typedef _Float16 half2v __attribute__((ext_vector_type(2)));
typedef float f32x4 __attribute__((ext_vector_type(4)));

// ---------------- CSR build (graph constant across layers) ----------------
__global__ void k_count(const int* __restrict__ edst, int* __restrict__ counts) {
    int e = blockIdx.x * blockDim.x + threadIdx.x;
    if (e >= NET) return;
    int d = (e < NE) ? edst[e] : (e - NE);   // self loops appended
    atomicAdd(&counts[d], 1);
}

__global__ __launch_bounds__(256) void k_scan1(const int* __restrict__ counts,
                                               int* __restrict__ part) {
    __shared__ int s[256];
    int t = threadIdx.x, i = blockIdx.x * 256 + t;
    s[t] = (i < NN) ? counts[i] : 0;
    __syncthreads();
    for (int off = 128; off > 0; off >>= 1) {
        if (t < off) s[t] += s[t + off];
        __syncthreads();
    }
    if (t == 0) part[blockIdx.x] = s[0];
}

__global__ __launch_bounds__(256) void k_scan2(int* __restrict__ part, int* __restrict__ offs) {
    __shared__ int s[256];
    int t = threadIdx.x;
    int v = (t < SCAN_NB) ? part[t] : 0;
    s[t] = v;
    __syncthreads();
    for (int off = 1; off < 256; off <<= 1) {
        int a = (t >= off) ? s[t - off] : 0;
        __syncthreads();
        s[t] += a;
        __syncthreads();
    }
    if (t < SCAN_NB) part[t] = s[t] - v;     // exclusive block offsets
    if (t == 255) offs[NN] = s[255];         // total (= NET)
}

__global__ __launch_bounds__(256) void k_scan3(const int* __restrict__ counts,
                                               const int* __restrict__ part,
                                               int* __restrict__ offs, int* __restrict__ cursor) {
    __shared__ int s[256];
    int t = threadIdx.x, i = blockIdx.x * 256 + t;
    int v = (i < NN) ? counts[i] : 0;
    s[t] = v;
    __syncthreads();
    for (int off = 1; off < 256; off <<= 1) {
        int a = (t >= off) ? s[t - off] : 0;
        __syncthreads();
        s[t] += a;
        __syncthreads();
    }
    if (i < NN) {
        int e = part[blockIdx.x] + s[t] - v;
        offs[i] = e;
        cursor[i] = e;
    }
}

__global__ void k_scatter(const int* __restrict__ esrc, const int* __restrict__ edst,
                          int* __restrict__ cursor, int* __restrict__ csr_src) {
    int e = blockIdx.x * blockDim.x + threadIdx.x;
    if (e >= NET) return;
    int s, d;
    if (e < NE) { s = esrc[e]; d = edst[e]; } else { s = e - NE; d = s; }
    int pos = atomicAdd(&cursor[d], 1);
    csr_src[pos] = s;
}

// ---------------- split fp32 -> f16 hi/lo pair ----------------
__global__ void k_split(const float* __restrict__ in, _Float16* __restrict__ hi,
                        _Float16* __restrict__ lo, int n) {
    int i = blockIdx.x * blockDim.x + threadIdx.x;
    int st = gridDim.x * blockDim.x;
    for (; i < n; i += st) {
        float v = in[i];
        _Float16 h = (_Float16)v;
        hi[i] = h;
        lo[i] = (_Float16)(v - (float)h);
    }
}

// ---------------- transpose + split weights: W[K][N] -> T[N][K] hi/lo (LDS-tiled) ----
__global__ __launch_bounds__(256) void k_prepw(const float* __restrict__ W,
                                               _Float16* __restrict__ Th,
                                               _Float16* __restrict__ Tl, int K, int N) {
    __shared__ float tile[32][33];
    int tx = threadIdx.x & 31, ty = threadIdx.x >> 5;
    int n0 = blockIdx.x * 32, k0 = blockIdx.y * 32;
    #pragma unroll
    for (int r = ty; r < 32; r += 8)
        tile[r][tx] = W[(size_t)(k0 + r) * N + n0 + tx];   // coalesced read
    __syncthreads();
    #pragma unroll
    for (int r = ty; r < 32; r += 8) {
        int n = n0 + r, k = k0 + tx;
        float v = tile[tx][r];
        _Float16 h = (_Float16)v;
        Th[(size_t)n * K + k] = h;                          // coalesced 64B segments
        Tl[(size_t)n * K + k] = (_Float16)(v - (float)h);
    }
}

// ---------------- per-node attention scalars: s = h . a ----------------
__global__ void k_scalars(const float* __restrict__ h, const float* __restrict__ a_src,
                          const float* __restrict__ a_dst, float* __restrict__ s_src,
                          float* __restrict__ s_dst) {
    int node = blockIdx.x * 4 + (threadIdx.x >> 6);
    int lane = threadIdx.x & 63;
    if (node >= NN) return;
    const float2* hr = (const float2*)(h + (size_t)node * 128) + lane;
    float2 hv = *hr;
    float2 as = *((const float2*)a_src + lane);
    float2 ad = *((const float2*)a_dst + lane);
    float ps = hv.x * as.x + hv.y * as.y;
    float pd = hv.x * ad.x + hv.y * ad.y;
    #pragma unroll
    for (int off = 32; off > 0; off >>= 1) {
        ps += __shfl_down(ps, off);
        pd += __shfl_down(pd, off);
    }
    if (lane == 0) { s_src[node] = ps; s_dst[node] = pd; }
}

// ---------------- fused segment-softmax + aggregate + bias + leaky ----------------
// 4-edge unroll (latency-bound gather); float2 per-lane row gather (1 load not 2).
__global__ void k_aggregate(const float* __restrict__ h, const float* __restrict__ s_src,
                            const float* __restrict__ s_dst, const int* __restrict__ offs,
                            const int* __restrict__ csr_src, const float* __restrict__ bias,
                            _Float16* __restrict__ xh, _Float16* __restrict__ xl) {
    int node = blockIdx.x * 4 + (threadIdx.x >> 6);
    int lane = threadIdx.x & 63;
    if (node >= NN) return;
    int p = offs[node], pe = offs[node + 1];
    float sd = s_dst[node];
    float den = 0.f, acc0 = 0.f, acc1 = 0.f;
    for (; p + 4 <= pe; p += 4) {
        int s0 = csr_src[p + 0], s1 = csr_src[p + 1];
        int s2 = csr_src[p + 2], s3 = csr_src[p + 3];
        float e0 = s_src[s0] + sd, e1 = s_src[s1] + sd;
        float e2 = s_src[s2] + sd, e3 = s_src[s3] + sd;
        float2 a0 = *((const float2*)(h + (size_t)s0 * 128) + lane);
        float2 a1 = *((const float2*)(h + (size_t)s1 * 128) + lane);
        float2 a2 = *((const float2*)(h + (size_t)s2 * 128) + lane);
        float2 a3 = *((const float2*)(h + (size_t)s3 * 128) + lane);
        e0 = (e0 > 0.f) ? e0 : 0.2f * e0;  float w0 = __expf(e0);
        e1 = (e1 > 0.f) ? e1 : 0.2f * e1;  float w1 = __expf(e1);
        e2 = (e2 > 0.f) ? e2 : 0.2f * e2;  float w2 = __expf(e2);
        e3 = (e3 > 0.f) ? e3 : 0.2f * e3;  float w3 = __expf(e3);
        den += (w0 + w1) + (w2 + w3);
        acc0 += w0 * a0.x + w1 * a1.x + w2 * a2.x + w3 * a3.x;
        acc1 += w0 * a0.y + w1 * a1.y + w2 * a2.y + w3 * a3.y;
    }
    for (; p < pe; ++p) {
        int src = csr_src[p];
        float e = s_src[src] + sd;
        e = (e > 0.f) ? e : 0.2f * e;
        float wgt = __expf(e);
        den += wgt;
        float2 av = *((const float2*)(h + (size_t)src * 128) + lane);
        acc0 += wgt * av.x;
        acc1 += wgt * av.y;
    }
    float inv = 1.f / den;                    // self-loop guarantees den > 0
    float2 bv = *((const float2*)bias + lane);
    float v0 = acc0 * inv + bv.x;
    float v1 = acc1 * inv + bv.y;
    v0 = (v0 > 0.f) ? v0 : 0.2f * v0;
    v1 = (v1 > 0.f) ? v1 : 0.2f * v1;
    _Float16 h0 = (_Float16)v0, h1 = (_Float16)v1;
    size_t base = (size_t)node * 128 + 2 * lane;
    *(half2v*)(xh + base) = (half2v){h0, h1};
    *(half2v*)(xl + base) = (half2v){(_Float16)(v0 - (float)h0), (_Float16)(v1 - (float)h1)};
}

// ---------------- split-f16 MFMA GEMM (R7 structure — measured best: 124 µs) ----------
// C[M][N] = act(A[M][K] @ B^T[N][K] + bias), A,B as f16 hi/lo pairs,
// A·B ≈ Ahi·Bhi + Ahi·Blo + Alo·Bhi (fp32 MFMA accumulate).
// 128x128 tile, 4 waves (2x2), each wave 64x64 = 4x4 of 16x16x32 MFMA. BK=32.
// VGPR staging (simple loads -> LDS stores): lowest VGPR count (72) of all
// variants tried -> most resident waves; compiler hoists next-tile loads
// across the barrier (implicit pipelining). Stride-40 LDS rows (16B aligned).
// NOTE: this layout has ~1.15e7 LDS bank-conflict cycles/dispatch — measured
// OFF the critical path (R8/R11 zero-conflict variants were SLOWER: 143/149
// vs 124 µs; limiter is wave-level latency hiding, not LDS throughput).
// XCD-aware 1D tile order: bid -> g=(bid&7)*per+(bid>>3), row-major tiles;
// contiguous tile runs per XCD keep A panel in that XCD's L2 (FETCH 197->56MB).
__global__ __launch_bounds__(256) void k_mgemm(
    const _Float16* __restrict__ Ahi, const _Float16* __restrict__ Alo,
    const _Float16* __restrict__ Bhi, const _Float16* __restrict__ Blo,
    const float* __restrict__ bias, float* __restrict__ Cf,
    _Float16* __restrict__ Chi, _Float16* __restrict__ Clo,
    int M, int N, int K, int relu, int split, int nx, int ntiles)
{
    __shared__ _Float16 sA[2][128][40];   // stride 40 (80B): 16B-aligned rows
    __shared__ _Float16 sB[2][128][40];

    int bid = blockIdx.x;
    int per = (ntiles + 7) >> 3;
    int g = (bid & 7) * per + (bid >> 3);
    if (g >= ntiles) return;
    int col0 = (g % nx) * 128;
    int row0 = (g / nx) * 128;

    int t = threadIdx.x;
    int w = t >> 6, lane = t & 63;
    int wm = (w & 1) * 64, wn = (w >> 1) * 64;
    int fr = lane & 15;
    int fq = lane >> 4;

    int srow = t >> 2;                // 0..63
    int scol = (t & 3) * 8;           // 0,8,16,24

    f32x4 acc[4][4];
    #pragma unroll
    for (int i = 0; i < 4; i++)
        #pragma unroll
        for (int j = 0; j < 4; j++) acc[i][j] = (f32x4){0.f, 0.f, 0.f, 0.f};

    for (int k0 = 0; k0 < K; k0 += 32) {
        if (k0) __syncthreads();
        #pragma unroll
        for (int c = 0; c < 2; ++c) {
            int r = srow + c * 64;
            int ga = row0 + r;
            half8 vh = {}, vl = {};
            if (ga < M) {
                vh = *(const half8*)(Ahi + (size_t)ga * K + k0 + scol);
                vl = *(const half8*)(Alo + (size_t)ga * K + k0 + scol);
            }
            *(half8*)&sA[0][r][scol] = vh;
            *(half8*)&sA[1][r][scol] = vl;
            int gb = col0 + r;        // N % 128 == 0 -> always in range
            *(half8*)&sB[0][r][scol] = *(const half8*)(Bhi + (size_t)gb * K + k0 + scol);
            *(half8*)&sB[1][r][scol] = *(const half8*)(Blo + (size_t)gb * K + k0 + scol);
        }
        __syncthreads();

        half8 bh[4], bl[4];
        #pragma unroll
        for (int ni = 0; ni < 4; ++ni) {
            bh[ni] = *(half8*)&sB[0][wn + ni * 16 + fr][fq * 8];
            bl[ni] = *(half8*)&sB[1][wn + ni * 16 + fr][fq * 8];
        }
        #pragma unroll
        for (int mi = 0; mi < 4; ++mi) {
            half8 ah = *(half8*)&sA[0][wm + mi * 16 + fr][fq * 8];
            half8 al = *(half8*)&sA[1][wm + mi * 16 + fr][fq * 8];
            #pragma unroll
            for (int ni = 0; ni < 4; ++ni) {
                acc[mi][ni] = __builtin_amdgcn_mfma_f32_16x16x32_f16(ah, bh[ni], acc[mi][ni], 0, 0, 0);
                acc[mi][ni] = __builtin_amdgcn_mfma_f32_16x16x32_f16(ah, bl[ni], acc[mi][ni], 0, 0, 0);
                acc[mi][ni] = __builtin_amdgcn_mfma_f32_16x16x32_f16(al, bh[ni], acc[mi][ni], 0, 0, 0);
            }
        }
    }

    // epilogue: C/D layout col=lane&15, row=quad*4+reg
    #pragma unroll
    for (int ni = 0; ni < 4; ++ni) {
        int gc = col0 + wn + ni * 16 + fr;
        float bv = bias ? bias[gc] : 0.f;
        #pragma unroll
        for (int mi = 0; mi < 4; ++mi) {
            #pragma unroll
            for (int r = 0; r < 4; ++r) {
                int gr = row0 + wm + mi * 16 + fq * 4 + r;
                if (gr >= M) continue;
                float v = acc[mi][ni][r] + bv;
                if (relu) v = (v > 0.f) ? v : 0.f;
                size_t idx = (size_t)gr * N + gc;
                if (split) {
                    _Float16 hh = (_Float16)v;
                    Chi[idx] = hh;
                    Clo[idx] = (_Float16)(v - (float)hh);
                } else {
                    Cf[idx] = v;
                }
            }
        }
    }
}

// ---------------- head: out[M x 4] = (Yh+Yl)[M x 512] @ Wo[512 x 4] + bo ----------------
__global__ __launch_bounds__(256) void k_head(const _Float16* __restrict__ Yh,
                                              const _Float16* __restrict__ Yl,
                                              const float* __restrict__ Wo,
                                              const float* __restrict__ bo,
                                              float* __restrict__ out, int M) {
    int node = blockIdx.x * 4 + (threadIdx.x >> 6);
    int lane = threadIdx.x & 63;
    if (node >= M) return;
    size_t base = (size_t)node * 512 + lane * 8;
    half8 hv = *(const half8*)(Yh + base);
    half8 lv = *(const half8*)(Yl + base);
    float a0 = 0.f, a1 = 0.f, a2 = 0.f, a3 = 0.f;
    #pragma unroll
    for (int i = 0; i < 8; i++) {
        float y = (float)hv[i] + (float)lv[i];
        float4 wv = *(const float4*)(Wo + (size_t)(lane * 8 + i) * 4);
        a0 += y * wv.x; a1 += y * wv.y;
        a2 += y * wv.z; a3 += y * wv.w;
    }
    #pragma unroll
    for (int off = 32; off > 0; off >>= 1) {
        a0 += __shfl_down(a0, off);
        a1 += __shfl_down(a1, off);
        a2 += __shfl_down(a2, off);
        a3 += __shfl_down(a3, off);
    }
    if (lane == 0) {
        float4 o;
        o.x = a0 + bo[0]; o.y = a1 + bo[1]; o.z = a2 + bo[2]; o.w = a3 + bo[3];
        *(float4*)(out + (size_t)node * 4) = o;
    }
}

extern "C" void kernel_launch(void* const* d_in, const int* in_sizes, int n_in,
                              void* d_out, int out_size, void* d_ws, size_t ws_size,
                              hipStream_t stream) {
    const float* x    = (const float*)d_in[0];
    const int*   eidx = (const int*)d_in[1];
    const float* cW   = (const float*)d_in[2];
    const float* caS  = (const float*)d_in[3];
    const float* caD  = (const float*)d_in[4];
    const float* cB   = (const float*)d_in[5];
    const float* W0   = (const float*)d_in[6];
    const float* b0   = (const float*)d_in[7];
    const float* W1   = (const float*)d_in[8];
    const float* b1   = (const float*)d_in[9];
    const float* W2   = (const float*)d_in[10];
    const float* b2   = (const float*)d_in[11];
    const float* Wo   = (const float*)d_in[12];
    const float* bo   = (const float*)d_in[13];
    (void)in_sizes; (void)n_in; (void)out_size;

    const int* esrc = eidx;
    const int* edst = eidx + NE;
    float* out = (float*)d_out;

    // ---- workspace bump allocator (256B aligned) ----
    char* w = (char*)d_ws;
    auto alloc = [&](size_t bytes) -> char* {
        char* p = w;
        w += (bytes + 255) & ~(size_t)255;
        return p;
    };
    _Float16* x0h  = (_Float16*)alloc((size_t)NN * 128 * 2);
    _Float16* x0l  = (_Float16*)alloc((size_t)NN * 128 * 2);
    _Float16* xh   = (_Float16*)alloc((size_t)NN * 128 * 2);
    _Float16* xl   = (_Float16*)alloc((size_t)NN * 128 * 2);
    float* hbuf    = (float*)alloc((size_t)NN * 128 * 4);
    float* ssrc    = (float*)alloc((size_t)NN * 4);
    float* sdst    = (float*)alloc((size_t)NN * 4);
    int*   counts  = (int*)  alloc((size_t)NN * 4);
    int*   offs    = (int*)  alloc((size_t)(NN + 1) * 4);
    int*   cursor  = (int*)  alloc((size_t)NN * 4);
    int*   csr     = (int*)  alloc((size_t)NET * 4);
    int*   part    = (int*)  alloc((size_t)SCAN_NB * 4);
    _Float16* cwh  = (_Float16*)alloc(3 * 128 * 128 * 2);
    _Float16* cwl  = (_Float16*)alloc(3 * 128 * 128 * 2);
    _Float16* w0h  = (_Float16*)alloc(512 * 128 * 2);
    _Float16* w0l  = (_Float16*)alloc(512 * 128 * 2);
    _Float16* w1h  = (_Float16*)alloc(512 * 512 * 2);
    _Float16* w1l  = (_Float16*)alloc(512 * 512 * 2);
    _Float16* w2h  = (_Float16*)alloc(512 * 512 * 2);
    _Float16* w2l  = (_Float16*)alloc(512 * 512 * 2);

    size_t used = (size_t)(w - (char*)d_ws);
    size_t rem = (ws_size > used) ? (ws_size - used) : 0;
    int chunk = (int)(rem / (4 * 512 * sizeof(_Float16)));
    if (chunk > NN) chunk = NN;
    if (chunk > 128) chunk &= ~127;
    if (chunk < 1) chunk = 1;
    _Float16* Y0h = (_Float16*)alloc((size_t)chunk * 512 * 2);
    _Float16* Y0l = (_Float16*)alloc((size_t)chunk * 512 * 2);
    _Float16* Y1h = (_Float16*)alloc((size_t)chunk * 512 * 2);
    _Float16* Y1l = (_Float16*)alloc((size_t)chunk * 512 * 2);

    auto gemm = [&](const _Float16* Ah, const _Float16* Al,
                    const _Float16* Bh, const _Float16* Bl,
                    const float* bias, float* Cf, _Float16* Ch, _Float16* Cl,
                    int M, int N, int K, int relu, int split) {
        int nx = N / 128;
        int ntiles = nx * ((M + 127) / 128);
        int nb = ((ntiles + 7) / 8) * 8;
        k_mgemm<<<nb, 256, 0, stream>>>(Ah, Al, Bh, Bl, bias, Cf, Ch, Cl,
                                        M, N, K, relu, split, nx, ntiles);
    };

    // ---- prep: split x, transpose+split weights ----
    k_split<<<2048, 256, 0, stream>>>(x, x0h, x0l, NN * 128);
    for (int L = 0; L < 3; ++L)
        k_prepw<<<dim3(128 / 32, 128 / 32), 256, 0, stream>>>(
            cW + (size_t)L * 128 * 128, cwh + (size_t)L * 128 * 128, cwl + (size_t)L * 128 * 128, 128, 128);
    k_prepw<<<dim3(512 / 32, 128 / 32), 256, 0, stream>>>(W0, w0h, w0l, 128, 512);
    k_prepw<<<dim3(512 / 32, 512 / 32), 256, 0, stream>>>(W1, w1h, w1l, 512, 512);
    k_prepw<<<dim3(512 / 32, 512 / 32), 256, 0, stream>>>(W2, w2h, w2l, 512, 512);

    // ---- build CSR once ----
    hipMemsetAsync(counts, 0, (size_t)NN * 4, stream);
    int eblocks = (NET + 255) / 256;
    k_count <<<eblocks, 256, 0, stream>>>(edst, counts);
    k_scan1 <<<SCAN_NB, 256, 0, stream>>>(counts, part);
    k_scan2 <<<1, 256, 0, stream>>>(part, offs);
    k_scan3 <<<SCAN_NB, 256, 0, stream>>>(counts, part, offs, cursor);
    k_scatter<<<eblocks, 256, 0, stream>>>(esrc, edst, cursor, csr);

    // ---- 3 GAT layers ----
    for (int L = 0; L < 3; ++L) {
        const _Float16* Ah = (L == 0) ? x0h : xh;
        const _Float16* Al = (L == 0) ? x0l : xl;
        gemm(Ah, Al, cwh + (size_t)L * 128 * 128, cwl + (size_t)L * 128 * 128,
             nullptr, hbuf, nullptr, nullptr, NN, 128, 128, 0, 0);
        k_scalars  <<<NN / 4, 256, 0, stream>>>(hbuf, caS + L * 128, caD + L * 128, ssrc, sdst);
        k_aggregate<<<NN / 4, 256, 0, stream>>>(hbuf, ssrc, sdst, offs, csr, cB + L * 128, xh, xl);
    }

    // ---- MLP head (chunked over nodes) ----
    for (int m0 = 0; m0 < NN; m0 += chunk) {
        int cm = imin(chunk, NN - m0);
        gemm(xh + (size_t)m0 * 128, xl + (size_t)m0 * 128, w0h, w0l, b0,
             nullptr, Y0h, Y0l, cm, 512, 128, 1, 1);
        gemm(Y0h, Y0l, w1h, w1l, b1, nullptr, Y1h, Y1l, cm, 512, 512, 1, 1);
        gemm(Y1h, Y1l, w2h, w2l, b2, nullptr, Y0h, Y0l, cm, 512, 512, 1, 1);
        k_head<<<(cm + 3) / 4, 256, 0, stream>>>(Y0h, Y0l, Wo, bo, out + (size_t)m0 * 4, cm);
    }
}